// Round 1
// baseline (695.367 us; speedup 1.0000x reference)
//
#include <hip/hip_runtime.h>

#define N 2000
#define NCLS 21
#define MAXPC 50
#define MAXPI 100
#define IOU_THR 0.7f
#define NEGV -1000000000.0f

// ---------------- decode ----------------
__global__ void decode_kernel(const float* __restrict__ rpn,
                              const float* __restrict__ deltas,
                              float* __restrict__ boxes) {
    int i = blockIdx.x * blockDim.x + threadIdx.x;
    if (i >= N) return;
    float y1 = rpn[i * 4 + 0], x1 = rpn[i * 4 + 1];
    float y2 = rpn[i * 4 + 2], x2 = rpn[i * 4 + 3];
    float h = y2 - y1, w = x2 - x1;
    float cy = y1 + 0.5f * h, cx = x1 + 0.5f * w;
    float dy = deltas[i * 4 + 0], dx = deltas[i * 4 + 1];
    float dh = deltas[i * 4 + 2], dw = deltas[i * 4 + 3];
    float pcy = dy * h + cy;
    float pcx = dx * w + cx;
    float ph = h * expf(dh);
    float pw = w * expf(dw);
    boxes[i * 4 + 0] = pcy - 0.5f * ph;
    boxes[i * 4 + 1] = pcx - 0.5f * pw;
    boxes[i * 4 + 2] = pcy + 0.5f * ph;
    boxes[i * 4 + 3] = pcx + 0.5f * pw;
}

// ---------------- stable descending sort per class (rank counting) ----------------
// order[c*N + rank] = original index; rank by (score desc, index asc) == argsort(-score) stable
__global__ void sort_kernel(const float* __restrict__ score, int* __restrict__ order) {
    __shared__ __align__(16) float s[N];
    int c = blockIdx.x;
    for (int i = threadIdx.x; i < N; i += blockDim.x)
        s[i] = score[i * NCLS + c];
    __syncthreads();
    const float4* s4 = (const float4*)s;
    for (int i = threadIdx.x; i < N; i += blockDim.x) {
        float si = s[i];
        int r = 0;
#pragma unroll 4
        for (int jj = 0; jj < N / 4; jj++) {
            float4 v = s4[jj];
            int j0 = jj * 4;
            r += (v.x > si) || (v.x == si && (j0 + 0) < i);
            r += (v.y > si) || (v.y == si && (j0 + 1) < i);
            r += (v.z > si) || (v.z == si && (j0 + 2) < i);
            r += (v.w > si) || (v.w == si && (j0 + 3) < i);
        }
        order[c * N + r] = i;
    }
}

// ---------------- greedy NMS per class, early-exit at 50 kept ----------------
__global__ void nms_kernel(const float* __restrict__ boxes,
                           const int* __restrict__ order,
                           int* __restrict__ keep_pos,   // [NCLS][MAXPC] sorted positions
                           int* __restrict__ keep_cnt) { // [NCLS]
    __shared__ float4 sbox[N];          // sorted boxes
    __shared__ unsigned char sup[N];
    __shared__ int s_i;
    int c = blockIdx.x;
    const float4* b4 = (const float4*)boxes;
    for (int i = threadIdx.x; i < N; i += blockDim.x) {
        sbox[i] = b4[order[c * N + i]];
        sup[i] = 0;
    }
    if (threadIdx.x == 0) s_i = 0;
    __syncthreads();

    int found = 0;
    while (true) {
        if (threadIdx.x == 0) {
            int i = s_i;
            while (i < N && sup[i]) i++;
            s_i = i;
        }
        __syncthreads();
        int i = s_i;
        if (i >= N) break;
        if (threadIdx.x == 0) keep_pos[c * MAXPC + found] = i;
        found++;
        float4 bi = sbox[i];
        float ai = (bi.z - bi.x) * (bi.w - bi.y);
        for (int j = i + 1 + threadIdx.x; j < N; j += blockDim.x) {
            if (!sup[j]) {
                float4 bj = sbox[j];
                float aj = (bj.z - bj.x) * (bj.w - bj.y);
                float iy1 = fmaxf(bi.x, bj.x);
                float ix1 = fmaxf(bi.y, bj.y);
                float iy2 = fminf(bi.z, bj.z);
                float ix2 = fminf(bi.w, bj.w);
                float inter = fmaxf(iy2 - iy1, 0.0f) * fmaxf(ix2 - ix1, 0.0f);
                float uni = ai + aj - inter;
                float iou = inter / fmaxf(uni, 1e-8f);
                if (iou > IOU_THR) sup[j] = 1;
            }
        }
        if (threadIdx.x == 0) s_i = i + 1;
        __syncthreads();
        if (found >= MAXPC) break;
    }
    if (threadIdx.x == 0) keep_cnt[c] = found;
}

// ---------------- global top-100 (stable: score desc, flat idx asc) ----------------
__global__ void topk_kernel(const float* __restrict__ boxes,
                            const int* __restrict__ order,
                            const int* __restrict__ keep_pos,
                            const int* __restrict__ keep_cnt,
                            const float* __restrict__ score,
                            float* __restrict__ out) {
    __shared__ float cs[NCLS * MAXPC + MAXPI];
    __shared__ int cf[NCLS * MAXPC + MAXPI];
    __shared__ int off[NCLS + 1];
    __shared__ int s_m;
    int tid = threadIdx.x;
    if (tid == 0) {
        int a = 0;
        for (int c = 0; c < NCLS; c++) { off[c] = a; a += keep_cnt[c]; }
        off[NCLS] = a;
        s_m = a;
    }
    __syncthreads();
    int M = s_m;
    for (int t = tid; t < M; t += blockDim.x) {
        int c = 0;
        while (c + 1 < NCLS && off[c + 1] <= t) c++;   // small linear search
        int k = t - off[c];
        int pos = keep_pos[c * MAXPC + k];
        int oi = order[c * N + pos];
        cs[t] = score[oi * NCLS + c];
        cf[t] = c * N + pos;
    }
    __syncthreads();
    // rare path: fewer than 100 valid -> fill with NEG entries in flat-index order
    if (tid == 0 && M < MAXPI) {
        int m = M;
        for (int flat = 0; flat < NCLS * N && m < MAXPI; flat++) {
            int c = flat / N, pos = flat % N;
            bool valid = false;
            int cn = keep_cnt[c];
            for (int k = 0; k < cn; k++)
                if (keep_pos[c * MAXPC + k] == pos) { valid = true; break; }
            if (!valid) { cs[m] = NEGV; cf[m] = flat; m++; }
        }
        s_m = m;
    }
    __syncthreads();
    M = s_m;
    const float4* b4 = (const float4*)boxes;
    for (int t = tid; t < M; t += blockDim.x) {
        float si = cs[t];
        int fi = cf[t];
        int r = 0;
        for (int j = 0; j < M; j++)
            r += (cs[j] > si) || (cs[j] == si && cf[j] < fi);
        if (r < MAXPI) {
            int c = fi / N, pos = fi % N;
            int oi = order[c * N + pos];
            float4 b = b4[oi];
            out[r * 4 + 0] = b.x;
            out[r * 4 + 1] = b.y;
            out[r * 4 + 2] = b.z;
            out[r * 4 + 3] = b.w;
            out[4 * MAXPI + r] = (float)c;
        }
    }
}

extern "C" void kernel_launch(void* const* d_in, const int* in_sizes, int n_in,
                              void* d_out, int out_size, void* d_ws, size_t ws_size,
                              hipStream_t stream) {
    const float* rpn    = (const float*)d_in[0];  // [2000,4]
    const float* deltas = (const float*)d_in[1];  // [2000,4]
    const float* score  = (const float*)d_in[2];  // [2000,21]
    float* out = (float*)d_out;                   // 400 box floats + 100 cls

    char* ws = (char*)d_ws;
    float* boxes  = (float*)(ws);                 // 2000*4 f = 32000 B
    int*   order  = (int*)(ws + 32000);           // 21*2000 i = 168000 B
    int*   keep_pos = (int*)(ws + 200064);        // 21*50 i = 4200 B
    int*   keep_cnt = (int*)(ws + 204288);        // 21 i

    decode_kernel<<<(N + 255) / 256, 256, 0, stream>>>(rpn, deltas, boxes);
    sort_kernel<<<NCLS, 256, 0, stream>>>(score, order);
    nms_kernel<<<NCLS, 256, 0, stream>>>(boxes, order, keep_pos, keep_cnt);
    topk_kernel<<<1, 1024, 0, stream>>>(boxes, order, keep_pos, keep_cnt, score, out);
}

// Round 2
// 266.280 us; speedup vs baseline: 2.6114x; 2.6114x over previous
//
#include <hip/hip_runtime.h>

#define N 2000
#define NCLS 21
#define MAXPC 50
#define MAXPI 100
#define IOU_THR 0.7f
#define NEGV -1000000000.0f

// ---------------- decode ----------------
__global__ void decode_kernel(const float* __restrict__ rpn,
                              const float* __restrict__ deltas,
                              float* __restrict__ boxes) {
    int i = blockIdx.x * blockDim.x + threadIdx.x;
    if (i >= N) return;
    float y1 = rpn[i * 4 + 0], x1 = rpn[i * 4 + 1];
    float y2 = rpn[i * 4 + 2], x2 = rpn[i * 4 + 3];
    float h = y2 - y1, w = x2 - x1;
    float cy = y1 + 0.5f * h, cx = x1 + 0.5f * w;
    float dy = deltas[i * 4 + 0], dx = deltas[i * 4 + 1];
    float dh = deltas[i * 4 + 2], dw = deltas[i * 4 + 3];
    float pcy = dy * h + cy;
    float pcx = dx * w + cx;
    float ph = h * expf(dh);
    float pw = w * expf(dw);
    boxes[i * 4 + 0] = pcy - 0.5f * ph;
    boxes[i * 4 + 1] = pcx - 0.5f * pw;
    boxes[i * 4 + 2] = pcy + 0.5f * ph;
    boxes[i * 4 + 3] = pcx + 0.5f * pw;
}

// ---------------- stable descending sort per class (rank counting) ----------------
// order[c*N + rank] = original index; rank by (score desc, index asc)
// Parallelization: grid (NCLS, 32); each block owns 64 rows i; each row is
// computed by 4 consecutive lanes, each scanning a disjoint quarter of j
// (125 float4 chunks), then shfl-reduced. Per-thread dependent-LDS chain is
// 125 iterations instead of 4000 -> latency-tolerant even at low occupancy.
__global__ void sort_kernel(const float* __restrict__ score, int* __restrict__ order) {
    __shared__ __align__(16) float s[N];
    int c = blockIdx.x;
    for (int i = threadIdx.x; i < N; i += blockDim.x)
        s[i] = score[i * NCLS + c];
    __syncthreads();

    int i = blockIdx.y * 64 + (threadIdx.x >> 2);
    int q = threadIdx.x & 3;
    if (i < N) {
        float si = s[i];
        const float4* s4 = (const float4*)s;
        int r = 0;
        int jj0 = q * 125;
#pragma unroll 5
        for (int jj = jj0; jj < jj0 + 125; jj++) {
            float4 v = s4[jj];
            int j0 = jj * 4;
            r += (v.x > si) || (v.x == si && (j0 + 0) < i);
            r += (v.y > si) || (v.y == si && (j0 + 1) < i);
            r += (v.z > si) || (v.z == si && (j0 + 2) < i);
            r += (v.w > si) || (v.w == si && (j0 + 3) < i);
        }
        r += __shfl_xor(r, 1);
        r += __shfl_xor(r, 2);
        if (q == 0) order[c * N + r] = i;
    }
}

// ---------------- greedy NMS per class, early-exit at 50 kept ----------------
__global__ void nms_kernel(const float* __restrict__ boxes,
                           const int* __restrict__ order,
                           int* __restrict__ keep_pos,   // [NCLS][MAXPC] sorted positions
                           int* __restrict__ keep_cnt) { // [NCLS]
    __shared__ float4 sbox[N];          // sorted boxes
    __shared__ unsigned char sup[N];
    __shared__ int s_i;
    int c = blockIdx.x;
    const float4* b4 = (const float4*)boxes;
    for (int i = threadIdx.x; i < N; i += blockDim.x) {
        sbox[i] = b4[order[c * N + i]];
        sup[i] = 0;
    }
    if (threadIdx.x == 0) s_i = 0;
    __syncthreads();

    int found = 0;
    while (true) {
        if (threadIdx.x == 0) {
            int i = s_i;
            while (i < N && sup[i]) i++;
            s_i = i;
        }
        __syncthreads();
        int i = s_i;
        if (i >= N) break;
        if (threadIdx.x == 0) keep_pos[c * MAXPC + found] = i;
        found++;
        float4 bi = sbox[i];
        float ai = (bi.z - bi.x) * (bi.w - bi.y);
        for (int j = i + 1 + threadIdx.x; j < N; j += blockDim.x) {
            if (!sup[j]) {
                float4 bj = sbox[j];
                float aj = (bj.z - bj.x) * (bj.w - bj.y);
                float iy1 = fmaxf(bi.x, bj.x);
                float ix1 = fmaxf(bi.y, bj.y);
                float iy2 = fminf(bi.z, bj.z);
                float ix2 = fminf(bi.w, bj.w);
                float inter = fmaxf(iy2 - iy1, 0.0f) * fmaxf(ix2 - ix1, 0.0f);
                float uni = ai + aj - inter;
                float iou = inter / fmaxf(uni, 1e-8f);
                if (iou > IOU_THR) sup[j] = 1;
            }
        }
        if (threadIdx.x == 0) s_i = i + 1;
        __syncthreads();
        if (found >= MAXPC) break;
    }
    if (threadIdx.x == 0) keep_cnt[c] = found;
}

// ---------------- global top-100 (stable: score desc, flat idx asc) ----------------
__global__ void topk_kernel(const float* __restrict__ boxes,
                            const int* __restrict__ order,
                            const int* __restrict__ keep_pos,
                            const int* __restrict__ keep_cnt,
                            const float* __restrict__ score,
                            float* __restrict__ out) {
    __shared__ float cs[NCLS * MAXPC + MAXPI];
    __shared__ int cf[NCLS * MAXPC + MAXPI];
    __shared__ int off[NCLS + 1];
    __shared__ int s_m;
    int tid = threadIdx.x;
    if (tid == 0) {
        int a = 0;
        for (int c = 0; c < NCLS; c++) { off[c] = a; a += keep_cnt[c]; }
        off[NCLS] = a;
        s_m = a;
    }
    __syncthreads();
    int M = s_m;
    for (int t = tid; t < M; t += blockDim.x) {
        int c = 0;
        while (c + 1 < NCLS && off[c + 1] <= t) c++;   // small linear search
        int k = t - off[c];
        int pos = keep_pos[c * MAXPC + k];
        int oi = order[c * N + pos];
        cs[t] = score[oi * NCLS + c];
        cf[t] = c * N + pos;
    }
    __syncthreads();
    // rare path: fewer than 100 valid -> fill with NEG entries in flat-index order
    if (tid == 0 && M < MAXPI) {
        int m = M;
        for (int flat = 0; flat < NCLS * N && m < MAXPI; flat++) {
            int c = flat / N, pos = flat % N;
            bool valid = false;
            int cn = keep_cnt[c];
            for (int k = 0; k < cn; k++)
                if (keep_pos[c * MAXPC + k] == pos) { valid = true; break; }
            if (!valid) { cs[m] = NEGV; cf[m] = flat; m++; }
        }
        s_m = m;
    }
    __syncthreads();
    M = s_m;
    const float4* b4 = (const float4*)boxes;
    for (int t = tid; t < M; t += blockDim.x) {
        float si = cs[t];
        int fi = cf[t];
        int r = 0;
        for (int j = 0; j < M; j++)
            r += (cs[j] > si) || (cs[j] == si && cf[j] < fi);
        if (r < MAXPI) {
            int c = fi / N, pos = fi % N;
            int oi = order[c * N + pos];
            float4 b = b4[oi];
            out[r * 4 + 0] = b.x;
            out[r * 4 + 1] = b.y;
            out[r * 4 + 2] = b.z;
            out[r * 4 + 3] = b.w;
            out[4 * MAXPI + r] = (float)c;
        }
    }
}

extern "C" void kernel_launch(void* const* d_in, const int* in_sizes, int n_in,
                              void* d_out, int out_size, void* d_ws, size_t ws_size,
                              hipStream_t stream) {
    const float* rpn    = (const float*)d_in[0];  // [2000,4]
    const float* deltas = (const float*)d_in[1];  // [2000,4]
    const float* score  = (const float*)d_in[2];  // [2000,21]
    float* out = (float*)d_out;                   // 400 box floats + 100 cls

    char* ws = (char*)d_ws;
    float* boxes  = (float*)(ws);                 // 2000*4 f = 32000 B
    int*   order  = (int*)(ws + 32000);           // 21*2000 i = 168000 B
    int*   keep_pos = (int*)(ws + 200064);        // 21*50 i = 4200 B
    int*   keep_cnt = (int*)(ws + 204288);        // 21 i

    decode_kernel<<<(N + 255) / 256, 256, 0, stream>>>(rpn, deltas, boxes);
    sort_kernel<<<dim3(NCLS, 32), 256, 0, stream>>>(score, order);
    nms_kernel<<<NCLS, 256, 0, stream>>>(boxes, order, keep_pos, keep_cnt);
    topk_kernel<<<1, 1024, 0, stream>>>(boxes, order, keep_pos, keep_cnt, score, out);
}

// Round 3
// 103.608 us; speedup vs baseline: 6.7115x; 2.5701x over previous
//
#include <hip/hip_runtime.h>

#define N 2000
#define NCLS 21
#define MAXPC 50
#define MAXPI 100
#define IOU_THR 0.7f
#define NEGV -1000000000.0f

typedef unsigned long long u64;
typedef unsigned int u32;

// monotone float -> uint32 map (order-preserving, incl. negatives)
__device__ __forceinline__ u32 sortable(float s) {
    u32 u = __float_as_uint(s);
    return ((int)u < 0) ? ~u : (u | 0x80000000u);
}

// ---------------- decode ----------------
__global__ void decode_kernel(const float* __restrict__ rpn,
                              const float* __restrict__ deltas,
                              float* __restrict__ boxes) {
    int i = blockIdx.x * blockDim.x + threadIdx.x;
    if (i >= N) return;
    float y1 = rpn[i * 4 + 0], x1 = rpn[i * 4 + 1];
    float y2 = rpn[i * 4 + 2], x2 = rpn[i * 4 + 3];
    float h = y2 - y1, w = x2 - x1;
    float cy = y1 + 0.5f * h, cx = x1 + 0.5f * w;
    float dy = deltas[i * 4 + 0], dx = deltas[i * 4 + 1];
    float dh = deltas[i * 4 + 2], dw = deltas[i * 4 + 3];
    float pcy = dy * h + cy;
    float pcx = dx * w + cx;
    float ph = h * expf(dh);
    float pw = w * expf(dw);
    boxes[i * 4 + 0] = pcy - 0.5f * ph;
    boxes[i * 4 + 1] = pcx - 0.5f * pw;
    boxes[i * 4 + 2] = pcy + 0.5f * ph;
    boxes[i * 4 + 3] = pcx + 0.5f * pw;
}

// ---------------- stable descending sort per class (branchless rank count) ---
// key = (sortable(score)<<32) | ~i  -> rank by single u64 compare.
// grid (NCLS, 32), 256 thr; 4 lanes per row i, each scans 500 j (250 x b128).
__global__ void sort_kernel(const float* __restrict__ score, int* __restrict__ order) {
    __shared__ __align__(16) u64 skey[N];
    int c = blockIdx.x;
    for (int i = threadIdx.x; i < N; i += blockDim.x) {
        u32 u = sortable(score[i * NCLS + c]);
        skey[i] = ((u64)u << 32) | (u32)(~i);
    }
    __syncthreads();
    int i = blockIdx.y * 64 + (threadIdx.x >> 2);
    int q = threadIdx.x & 3;
    if (i < N) {
        u64 ki = skey[i];
        const ulonglong2* s2 = (const ulonglong2*)skey;
        int r = 0;
        int jj0 = q * 250;
#pragma unroll 4
        for (int jj = jj0; jj < jj0 + 250; jj++) {
            ulonglong2 v = s2[jj];
            r += (v.x > ki);
            r += (v.y > ki);
        }
        r += __shfl_xor(r, 1);
        r += __shfl_xor(r, 2);
        if (q == 0) order[c * N + r] = i;
    }
}

// ---------------- greedy NMS, one wave per class, chunked in-wave resolve ----
__global__ void nms_kernel(const float* __restrict__ boxes,
                           const int* __restrict__ order,
                           const float* __restrict__ score,
                           int* __restrict__ keep_pos,   // [NCLS][MAXPC]
                           int* __restrict__ keep_cnt,   // [NCLS]
                           u64* __restrict__ cand_key) { // [NCLS][MAXPC]
    __shared__ float4 kbox[MAXPC];
    int c = blockIdx.x;
    int lane = threadIdx.x;
    const float4* b4 = (const float4*)boxes;
    int nk = 0;
    const int NCH = (N + 63) / 64;
    for (int chunk = 0; chunk < NCH && nk < MAXPC; chunk++) {
        __syncthreads();   // prior kbox writes visible for kept-check
        int pos = chunk * 64 + lane;
        bool valid = pos < N;
        int oi = valid ? order[c * N + pos] : 0;
        float4 b = b4[oi];
        float ar = (b.z - b.x) * (b.w - b.y);
        bool sup = !valid;
        for (int k = 0; k < nk; k++) {     // vs already-kept (broadcast LDS)
            float4 kb = kbox[k];
            float ka = (kb.z - kb.x) * (kb.w - kb.y);
            float iy1 = fmaxf(b.x, kb.x), ix1 = fmaxf(b.y, kb.y);
            float iy2 = fminf(b.z, kb.z), ix2 = fminf(b.w, kb.w);
            float inter = fmaxf(iy2 - iy1, 0.f) * fmaxf(ix2 - ix1, 0.f);
            float iou = inter / fmaxf(ar + ka - inter, 1e-8f);
            sup = sup || (iou > IOU_THR);
        }
        u64 alive = __ballot(!sup);
        while (alive && nk < MAXPC) {      // in-wave greedy resolve
            int l = __ffsll((unsigned long long)alive) - 1;
            if (lane == l) {
                kbox[nk] = b;
                keep_pos[c * MAXPC + nk] = pos;
                u32 u = sortable(score[oi * NCLS + c]);
                cand_key[c * MAXPC + nk] = ((u64)u << 32) | (u32)(~(c * N + pos));
            }
            float bxx = __shfl(b.x, l), bxy = __shfl(b.y, l);
            float bxz = __shfl(b.z, l), bxw = __shfl(b.w, l);
            nk++;
            if (lane > l && !sup) {
                float ka = (bxz - bxx) * (bxw - bxy);
                float iy1 = fmaxf(b.x, bxx), ix1 = fmaxf(b.y, bxy);
                float iy2 = fminf(b.z, bxz), ix2 = fminf(b.w, bxw);
                float inter = fmaxf(iy2 - iy1, 0.f) * fmaxf(ix2 - ix1, 0.f);
                float iou = inter / fmaxf(ar + ka - inter, 1e-8f);
                if (iou > IOU_THR) sup = true;
            }
            u64 nb = __ballot(!sup);
            alive = (l >= 63) ? 0ull : (nb & (~0ull << (l + 1)));
        }
    }
    if (lane == 0) keep_cnt[c] = nk;
}

// ---------------- global top-100 (branchless key ranking, 8 lanes/entry) ----
__global__ void topk_kernel(const float* __restrict__ boxes,
                            const int* __restrict__ order,
                            const int* __restrict__ keep_pos,
                            const int* __restrict__ keep_cnt,
                            const u64* __restrict__ cand_key,
                            float* __restrict__ out) {
    __shared__ __align__(16) u64 skey[NCLS * MAXPC + MAXPI];
    __shared__ int off[NCLS + 1];
    __shared__ int s_m;
    int tid = threadIdx.x;
    if (tid == 0) {
        int a = 0;
        for (int cc = 0; cc < NCLS; cc++) { off[cc] = a; a += keep_cnt[cc]; }
        off[NCLS] = a; s_m = a;
    }
    __syncthreads();
    int M = s_m;
    for (int t = tid; t < M; t += blockDim.x) {
        int cc = 0;
        while (cc + 1 < NCLS && off[cc + 1] <= t) cc++;
        skey[t] = cand_key[cc * MAXPC + (t - off[cc])];
    }
    __syncthreads();
    // rare path: M<100 -> fill with NEG entries, smallest flat first.
    // Smallest flats are class-0 positions; among pos 0..149 at most 50 are
    // kept, so >=100 invalid slots exist there — always sufficient.
    if (tid == 0 && M < MAXPI) {
        int m = M;
        int cnt0 = keep_cnt[0];
        for (int pos = 0; pos < 150 && m < MAXPI; pos++) {
            bool valid = false;
            for (int k = 0; k < cnt0; k++)
                if (keep_pos[k] == pos) { valid = true; break; }
            if (!valid) {
                u32 u = sortable(NEGV);
                skey[m++] = ((u64)u << 32) | (u32)(~pos);   // flat = pos (class 0)
            }
        }
        s_m = m;
    }
    __syncthreads();
    M = s_m;
    int g = tid & 7;
    int per = (M + 7) / 8;
    const float4* b4 = (const float4*)boxes;
    for (int t = tid >> 3; t < M; t += 128) {
        u64 ki = skey[t];
        int lo = g * per, hi = min(lo + per, M);
        int r = 0;
#pragma unroll 4
        for (int j = lo; j < hi; j++)
            r += (skey[j] > ki);
        r += __shfl_xor(r, 1);
        r += __shfl_xor(r, 2);
        r += __shfl_xor(r, 4);
        if (g == 0 && r < MAXPI) {
            int flat = (int)(~(u32)ki);      // recover flat index from key
            int cc = flat / N, pos = flat - cc * N;
            int oi = order[cc * N + pos];
            float4 b = b4[oi];
            out[r * 4 + 0] = b.x;
            out[r * 4 + 1] = b.y;
            out[r * 4 + 2] = b.z;
            out[r * 4 + 3] = b.w;
            out[4 * MAXPI + r] = (float)cc;
        }
    }
}

extern "C" void kernel_launch(void* const* d_in, const int* in_sizes, int n_in,
                              void* d_out, int out_size, void* d_ws, size_t ws_size,
                              hipStream_t stream) {
    const float* rpn    = (const float*)d_in[0];  // [2000,4]
    const float* deltas = (const float*)d_in[1];  // [2000,4]
    const float* score  = (const float*)d_in[2];  // [2000,21]
    float* out = (float*)d_out;                   // 400 box floats + 100 cls

    char* ws = (char*)d_ws;
    float* boxes   = (float*)(ws);                // 32000 B
    int*   order   = (int*)(ws + 32000);          // 168000 B
    u64*   candk   = (u64*)(ws + 200000);         // 8400 B (8-aligned)
    int*   keep_pos= (int*)(ws + 208400);         // 4200 B
    int*   keep_cnt= (int*)(ws + 212600);         // 84 B

    decode_kernel<<<(N + 255) / 256, 256, 0, stream>>>(rpn, deltas, boxes);
    sort_kernel<<<dim3(NCLS, 32), 256, 0, stream>>>(score, order);
    nms_kernel<<<NCLS, 64, 0, stream>>>(boxes, order, score, keep_pos, keep_cnt, candk);
    topk_kernel<<<1, 1024, 0, stream>>>(boxes, order, keep_pos, keep_cnt, candk, out);
}

// Round 4
// 48.490 us; speedup vs baseline: 14.3404x; 2.1367x over previous
//
#include <hip/hip_runtime.h>

#define N 2000
#define NCLS 21
#define MAXPC 50
#define MAXPI 100
#define IOU_THR 0.7f
#define NEGV -1000000000.0f

typedef unsigned long long u64;
typedef unsigned int u32;

// monotone float -> uint32 map (order-preserving, incl. negatives)
__device__ __forceinline__ u32 sortable(float s) {
    u32 u = __float_as_uint(s);
    return ((int)u < 0) ? ~u : (u | 0x80000000u);
}

// decode one box on the fly (bit-identical to reference formula)
__device__ __forceinline__ float4 decode_one(const float* __restrict__ rpn,
                                             const float* __restrict__ deltas, int i) {
    float4 p = ((const float4*)rpn)[i];
    float4 d = ((const float4*)deltas)[i];
    float h = p.z - p.x, w = p.w - p.y;
    float cy = p.x + 0.5f * h, cx = p.y + 0.5f * w;
    float pcy = d.x * h + cy;
    float pcx = d.y * w + cx;
    float ph = h * expf(d.z);
    float pw = w * expf(d.w);
    return make_float4(pcy - 0.5f * ph, pcx - 0.5f * pw, pcy + 0.5f * ph, pcx + 0.5f * pw);
}

// ---------------- stable descending sort per class (branchless rank count) ---
// key = (sortable(score)<<32) | ~i  -> rank by single u64 compare.
// grid (NCLS, 32), 256 thr; 4 lanes per row i, each scans 500 j (250 x b128).
// Within a wave, 16 lanes of the same quad-slot read the same LDS address ->
// broadcast, conflict-free.
__global__ void sort_kernel(const float* __restrict__ score, int* __restrict__ order) {
    __shared__ __align__(16) u64 skey[N];
    int c = blockIdx.x;
    for (int i = threadIdx.x; i < N; i += blockDim.x) {
        u32 u = sortable(score[i * NCLS + c]);
        skey[i] = ((u64)u << 32) | (u32)(~i);
    }
    __syncthreads();
    int i = blockIdx.y * 64 + (threadIdx.x >> 2);
    int q = threadIdx.x & 3;
    if (i < N) {
        u64 ki = skey[i];
        const ulonglong2* s2 = (const ulonglong2*)skey;
        int r = 0;
        int jj0 = q * 250;
#pragma unroll 4
        for (int jj = jj0; jj < jj0 + 250; jj++) {
            ulonglong2 v = s2[jj];
            r += (v.x > ki);
            r += (v.y > ki);
        }
        r += __shfl_xor(r, 1);
        r += __shfl_xor(r, 2);
        if (q == 0) order[c * N + r] = i;
    }
}

// ---------------- greedy NMS, one wave per class, chunked in-wave resolve ----
__global__ void nms_kernel(const float* __restrict__ rpn,
                           const float* __restrict__ deltas,
                           const int* __restrict__ order,
                           const float* __restrict__ score,
                           int* __restrict__ keep_pos,   // [NCLS][MAXPC]
                           int* __restrict__ keep_cnt,   // [NCLS]
                           u64* __restrict__ cand_key) { // [NCLS][MAXPC]
    __shared__ float4 kbox[MAXPC];
    int c = blockIdx.x;
    int lane = threadIdx.x;
    int nk = 0;
    const int NCH = (N + 63) / 64;
    for (int chunk = 0; chunk < NCH && nk < MAXPC; chunk++) {
        __syncthreads();   // prior kbox writes visible for kept-check
        int pos = chunk * 64 + lane;
        bool valid = pos < N;
        int oi = valid ? order[c * N + pos] : 0;
        float4 b = decode_one(rpn, deltas, oi);
        float ar = (b.z - b.x) * (b.w - b.y);
        bool sup = !valid;
        for (int k = 0; k < nk; k++) {     // vs already-kept (broadcast LDS)
            float4 kb = kbox[k];
            float ka = (kb.z - kb.x) * (kb.w - kb.y);
            float iy1 = fmaxf(b.x, kb.x), ix1 = fmaxf(b.y, kb.y);
            float iy2 = fminf(b.z, kb.z), ix2 = fminf(b.w, kb.w);
            float inter = fmaxf(iy2 - iy1, 0.f) * fmaxf(ix2 - ix1, 0.f);
            float iou = inter / fmaxf(ar + ka - inter, 1e-8f);
            sup = sup || (iou > IOU_THR);
        }
        u64 alive = __ballot(!sup);
        while (alive && nk < MAXPC) {      // in-wave greedy resolve
            int l = __ffsll((unsigned long long)alive) - 1;
            if (lane == l) {
                kbox[nk] = b;
                keep_pos[c * MAXPC + nk] = pos;
                u32 u = sortable(score[oi * NCLS + c]);
                cand_key[c * MAXPC + nk] = ((u64)u << 32) | (u32)(~(c * N + pos));
            }
            float bxx = __shfl(b.x, l), bxy = __shfl(b.y, l);
            float bxz = __shfl(b.z, l), bxw = __shfl(b.w, l);
            nk++;
            if (lane > l && !sup) {
                float ka = (bxz - bxx) * (bxw - bxy);
                float iy1 = fmaxf(b.x, bxx), ix1 = fmaxf(b.y, bxy);
                float iy2 = fminf(b.z, bxz), ix2 = fminf(b.w, bxw);
                float inter = fmaxf(iy2 - iy1, 0.f) * fmaxf(ix2 - ix1, 0.f);
                float iou = inter / fmaxf(ar + ka - inter, 1e-8f);
                if (iou > IOU_THR) sup = true;
            }
            u64 nb = __ballot(!sup);
            alive = (l >= 63) ? 0ull : (nb & (~0ull << (l + 1)));
        }
    }
    if (lane == 0) keep_cnt[c] = nk;
}

// ---------------- global top-100: per-class block, binary-search ranking -----
// Class lists are sorted descending (NMS emits in sorted-position order), so
// rank(c,k) = k + sum over other classes of (count of keys > ki) via 6-step
// binary searches in <=50-element LDS lists.
__global__ void topk_kernel(const float* __restrict__ rpn,
                            const float* __restrict__ deltas,
                            const int* __restrict__ order,
                            const int* __restrict__ keep_pos,
                            const int* __restrict__ keep_cnt,
                            const u64* __restrict__ cand_key,
                            float* __restrict__ out) {
    __shared__ u64 keys[NCLS][MAXPC];
    __shared__ int cnt[NCLS];
    int c = blockIdx.x;
    int lane = threadIdx.x;
    for (int t = lane; t < NCLS * MAXPC; t += 64)
        keys[t / MAXPC][t % MAXPC] = cand_key[t];
    if (lane < NCLS) cnt[lane] = keep_cnt[lane];
    __syncthreads();

    int M = 0;
#pragma unroll
    for (int cc = 0; cc < NCLS; cc++) M += cnt[cc];

    if (lane < cnt[c]) {
        u64 ki = keys[c][lane];
        int r = lane;                        // rank within own (descending) list
#pragma unroll
        for (int cc = 0; cc < NCLS; cc++) {
            if (cc == c) continue;
            int lo = 0, hi = cnt[cc];
            while (lo < hi) {                // count of keys[cc][*] > ki
                int mid = (lo + hi) >> 1;
                if (keys[cc][mid] > ki) lo = mid + 1; else hi = mid;
            }
            r += lo;
        }
        if (r < MAXPI) {
            int flat = (int)(~(u32)ki);
            int pos = flat - c * N;
            int oi = order[c * N + pos];
            float4 b = decode_one(rpn, deltas, oi);
            out[r * 4 + 0] = b.x;
            out[r * 4 + 1] = b.y;
            out[r * 4 + 2] = b.z;
            out[r * 4 + 3] = b.w;
            out[4 * MAXPI + r] = (float)c;
        }
    }

    // rare path: M<100 -> fill with NEG entries, smallest flat first (class 0
    // positions; among pos 0..149 at most 50 are kept -> >=100 invalid slots).
    if (c == 0 && lane == 0 && M < MAXPI) {
        int m = M;
        int cnt0 = cnt[0];
        for (int pos = 0; pos < 150 && m < MAXPI; pos++) {
            bool valid = false;
            for (int k = 0; k < cnt0; k++)
                if (keep_pos[k] == pos) { valid = true; break; }
            if (!valid) {
                int oi = order[pos];
                float4 b = decode_one(rpn, deltas, oi);
                out[m * 4 + 0] = b.x;
                out[m * 4 + 1] = b.y;
                out[m * 4 + 2] = b.z;
                out[m * 4 + 3] = b.w;
                out[4 * MAXPI + m] = 0.0f;
                m++;
            }
        }
    }
}

extern "C" void kernel_launch(void* const* d_in, const int* in_sizes, int n_in,
                              void* d_out, int out_size, void* d_ws, size_t ws_size,
                              hipStream_t stream) {
    const float* rpn    = (const float*)d_in[0];  // [2000,4]
    const float* deltas = (const float*)d_in[1];  // [2000,4]
    const float* score  = (const float*)d_in[2];  // [2000,21]
    float* out = (float*)d_out;                   // 400 box floats + 100 cls

    char* ws = (char*)d_ws;
    int*   order    = (int*)(ws);                 // 168000 B
    u64*   candk    = (u64*)(ws + 168000);        // 8400 B (8-aligned)
    int*   keep_pos = (int*)(ws + 176400);        // 4200 B
    int*   keep_cnt = (int*)(ws + 180600);        // 84 B

    sort_kernel<<<dim3(NCLS, 32), 256, 0, stream>>>(score, order);
    nms_kernel<<<NCLS, 64, 0, stream>>>(rpn, deltas, order, score, keep_pos, keep_cnt, candk);
    topk_kernel<<<NCLS, 64, 0, stream>>>(rpn, deltas, order, keep_pos, keep_cnt, candk, out);
}